// Round 5
// baseline (19553.020 us; speedup 1.0000x reference)
//
#include <hip/hip_runtime.h>
#include <math.h>

#define BATCH 16
#define HID   128
#define NX    128
#define NF    4
#define NT    64
#define MODES 96
#define OM    (5 * HID)     // 640 fused W rows (F + 4*G)
#define NWG   256
#define TPB   512
#define ZSZ   ((size_t)BATCH * NX * HID)

// ---------------------------------------------------------------------------
// Tables: C[m][x]=cos(2pi k_m x/128), S=sin, k_m=(80+m)%128; T2x[x][m]={c,s}
// ---------------------------------------------------------------------------
__global__ void k_tables(float* __restrict__ C, float* __restrict__ S,
                         float2* __restrict__ T2x) {
    int m = blockIdx.x, x = threadIdx.x;
    if (x < NX) {
        int k = (80 + m) % NX;
        float ang = (float)((k * x) & (NX - 1)) * (2.0f * (float)M_PI / (float)NX);
        float c = cosf(ang), s = sinf(ang);
        C[m * NX + x] = c;
        S[m * NX + x] = s;
        T2x[x * MODES + m] = make_float2(c, s);
    }
}

// ---------------------------------------------------------------------------
// dxi[t][b][x][n] = xi[b,n,x,t+1] - xi[b,n,x,t]
// ---------------------------------------------------------------------------
__global__ void k_dxi(const float* __restrict__ xi, float* __restrict__ dxi) {
    int idx = blockIdx.x * blockDim.x + threadIdx.x;
    const int total = (NT - 1) * BATCH * NX * NF;
    if (idx < total) {
        int n = idx & (NF - 1);
        int x = (idx >> 2) & (NX - 1);
        int b = (idx >> 9) & (BATCH - 1);
        int t = idx >> 13;
        const float* base = xi + (((size_t)b * NF + n) * NX + x) * NT;
        dxi[idx] = base[t + 1] - base[t];
    }
}

// ---------------------------------------------------------------------------
// Wt[h][om], om = g*128+o: g=0 -> WF[o][h]; g=1..4 -> WG[o][g-1][h]
// ---------------------------------------------------------------------------
__global__ void k_wt(const float* __restrict__ WF, const float* __restrict__ WG,
                     float* __restrict__ Wt) {
    __shared__ float t[32][33];
    int g = blockIdx.z;
    int h0 = blockIdx.x * 32, o0 = blockIdx.y * 32;
    int tx = threadIdx.x, ty = threadIdx.y;
    #pragma unroll
    for (int j = 0; j < 32; j += 8) {
        int o = o0 + ty + j;
        t[ty + j][tx] = (g == 0) ? WF[(size_t)o * HID + h0 + tx]
                                 : WG[((size_t)o * NF + (g - 1)) * HID + h0 + tx];
    }
    __syncthreads();
    #pragma unroll
    for (int j = 0; j < 32; j += 8)
        Wt[(size_t)(h0 + ty + j) * OM + g * HID + o0 + tx] = t[tx][ty + j];
}

// ---------------------------------------------------------------------------
// At2[m][h][o] = {A[0][m][o][h], A[1][m][o][h]}
// ---------------------------------------------------------------------------
__global__ void k_at2(const float* __restrict__ A, float2* __restrict__ At2) {
    __shared__ float t0[32][33], t1[32][33];
    int m = blockIdx.z;
    int h0 = blockIdx.x * 32, o0 = blockIdx.y * 32;
    int tx = threadIdx.x, ty = threadIdx.y;
    const float* A0 = A + (size_t)m * HID * HID;
    const float* A1 = A0 + (size_t)MODES * HID * HID;
    #pragma unroll
    for (int j = 0; j < 32; j += 8) {
        t0[ty + j][tx] = A0[(size_t)(o0 + ty + j) * HID + h0 + tx];
        t1[ty + j][tx] = A1[(size_t)(o0 + ty + j) * HID + h0 + tx];
    }
    __syncthreads();
    #pragma unroll
    for (int j = 0; j < 32; j += 8)
        At2[((size_t)m * HID + h0 + ty + j) * HID + o0 + tx] =
            make_float2(t0[tx][ty + j], t1[tx][ty + j]);
}

// ---------------------------------------------------------------------------
// Persistent solver: 256 WGs x 512 thr, grid barrier via ws atomics.
// ---------------------------------------------------------------------------
__global__ __launch_bounds__(TPB, 2) void k_persist(
    const float* __restrict__ z0, const float* __restrict__ Ct,
    const float* __restrict__ St, const float2* __restrict__ T2x,
    const float* __restrict__ Wt, const float2* __restrict__ At2,
    const float* __restrict__ dxi, float* __restrict__ va,
    float* __restrict__ vb, float* __restrict__ Hc,
    float* __restrict__ hf, float* __restrict__ zbuf,
    float* __restrict__ out, int* __restrict__ barc)
{
    __shared__ float Cs[MODES][8];
    __shared__ float Ss[MODES][8];
    __shared__ float zsh[HID][9];
    __shared__ float dxs[8][NF];
    __shared__ float scratch[16512];   // union: zl[128][129] / Hcl[128][9] / vsr+vsi / ftile

    const int w = blockIdx.x;
    const int t = threadIdx.x;
    const int b = w >> 4;
    const int sub = w & 15;
    const int xg0 = sub * 8;

    int nbar = 0;
    auto bar = [&]() {
        ++nbar;
        __syncthreads();
        if (t == 0) {
            __threadfence();
            __hip_atomic_fetch_add(barc, 1, __ATOMIC_RELEASE, __HIP_MEMORY_SCOPE_AGENT);
            while (__hip_atomic_load(barc, __ATOMIC_ACQUIRE, __HIP_MEMORY_SCOPE_AGENT)
                   < NWG * nbar)
                __builtin_amdgcn_s_sleep(2);
        }
        __syncthreads();
    };

    // ---- persistent P1 trig tables for this WG's x-tile ----
    for (int i = t; i < MODES * 8; i += TPB) {
        int m = i >> 3, xl = i & 7;
        Cs[m][xl] = Ct[m * NX + xg0 + xl];
        Ss[m][xl] = St[m * NX + xg0 + xl];
    }

    // ---- v0 phase: WG=(b, mg=sub) computes v0[b][c][6 m's][h] ----
    {
        float* zl = scratch;   // [128][129]
        for (int k = 0; k < 32; ++k) {
            int idx = t + k * TPB;
            zl[(idx >> 7) * 129 + (idx & 127)] = z0[(size_t)b * HID * NX + idx];
        }
        __syncthreads();
        int h = t & 127, q = t >> 7;
        int c = q & 1, mq = q >> 1;
        const float* Tb = c ? St : Ct;
        #pragma unroll
        for (int j = 0; j < 3; ++j) {
            int m = sub * 6 + mq * 3 + j;
            float acc = 0.f;
            #pragma unroll 4
            for (int x = 0; x < NX; ++x)
                acc += zl[h * 129 + x] * Tb[m * NX + x];
            if (c) acc = -acc;
            va[(((size_t)b * 2 + c) * MODES + m) * HID + h] = acc;
        }
    }
    bar();

    float* vcur = va;
    float* vnxt = vb;

    for (int step = 0; step < NT; ++step) {
        const int last = (step == NT - 1);

        // ---- P1: IDFT -> zsh + zbuf slice ----
        {
            if (!last && t < 32)
                dxs[t >> 2][t & 3] =
                    dxi[(((size_t)step * BATCH + b) * NX + xg0 + (t >> 2)) * NF + (t & 3)];
            int h = t & 127, xp = t >> 7;
            int x0 = xp * 2;
            const float* vr = vcur + ((size_t)b * 2) * MODES * HID + h;
            const float* vi = vr + (size_t)MODES * HID;
            float a0 = 0.f, a1 = 0.f;
            #pragma unroll 4
            for (int m = 0; m < MODES; ++m) {
                float r = vr[m * HID], im = vi[m * HID];
                a0 += r * Cs[m][x0]     - im * Ss[m][x0];
                a1 += r * Cs[m][x0 + 1] - im * Ss[m][x0 + 1];
            }
            a0 *= 0.0078125f; a1 *= 0.0078125f;
            zsh[h][x0] = a0; zsh[h][x0 + 1] = a1;
            float* zsl = zbuf + (size_t)(step & 15) * ZSZ + ((size_t)b * NX + xg0) * HID;
            zsl[(size_t)x0 * HID + h] = a0;
            zsl[(size_t)(x0 + 1) * HID + h] = a1;
        }
        __syncthreads();
        if (last) { bar(); break; }

        // ---- P2 (WG-local after P1): W-GEMM + tanh + dxi combine -> Hc ----
        {
            int x = t >> 6, oml = t & 63;
            float acc[10] = {0,0,0,0,0,0,0,0,0,0};
            const float* wp = Wt + oml;
            #pragma unroll 2
            for (int h = 0; h < HID; ++h) {
                float zv = zsh[h][x];                 // wave-broadcast
                const float* wr = wp + (size_t)h * OM;
                #pragma unroll
                for (int j = 0; j < 10; ++j)
                    acc[j] += wr[j * 64] * zv;
            }
            float d0 = dxs[x][0], d1 = dxs[x][1], d2 = dxs[x][2], d3 = dxs[x][3];
            #pragma unroll
            for (int oh = 0; oh < 2; ++oh) {
                float hv = tanhf(acc[oh])
                         + tanhf(acc[2 + oh]) * d0
                         + tanhf(acc[4 + oh]) * d1
                         + tanhf(acc[6 + oh]) * d2
                         + tanhf(acc[8 + oh]) * d3;
                Hc[((size_t)b * NX + xg0 + x) * HID + oh * 64 + oml] = hv;
            }
        }
        bar();

        // ---- P3a: DFT of Hc -> hf.  WG=(b, o-tile=sub) ----
        {
            float* Hcl = scratch;   // [128][9]
            #pragma unroll
            for (int k = 0; k < 2; ++k) {
                int idx = t + k * TPB;
                int ol = idx & 7, xx = idx >> 3;
                Hcl[xx * 9 + ol] = Hc[((size_t)b * NX + xx) * HID + sub * 8 + ol];
            }
            __syncthreads();
            int m1 = t & 63, op = t >> 6;
            bool two = (m1 < 32);
            int m2 = m1 + 64;
            float fre1 = 0, fim1 = 0, fre2 = 0, fim2 = 0;
            #pragma unroll 2
            for (int x = 0; x < NX; ++x) {
                float hv = Hcl[x * 9 + op];           // wave-broadcast
                float2 ta = T2x[x * MODES + m1];      // coalesced
                fre1 += hv * ta.x; fim1 -= hv * ta.y;
                if (two) {
                    float2 tb2 = T2x[x * MODES + m2];
                    fre2 += hv * tb2.x; fim2 -= hv * tb2.y;
                }
            }
            int o = sub * 8 + op;
            hf[(((size_t)b * 2 + 0) * HID + o) * MODES + m1] = fre1;
            hf[(((size_t)b * 2 + 1) * HID + o) * MODES + m1] = fim1;
            if (two) {
                hf[(((size_t)b * 2 + 0) * HID + o) * MODES + m2] = fre2;
                hf[(((size_t)b * 2 + 1) * HID + o) * MODES + m2] = fim2;
            }
            __syncthreads();
        }
        bar();

        // ---- P3b: Av + update (w<192); flush (w>=192, every 16 steps) ----
        if (w < 192) {
            int m = w >> 1, oh = w & 1;
            float* vsr = scratch;          // [16][128]
            float* vsi = scratch + 2048;
            #pragma unroll
            for (int k = 0; k < 8; ++k) {
                int idx = t + k * TPB;
                int h = idx & 127, bc = idx >> 7;
                int bb = bc >> 1, c = bc & 1;
                float vv = vcur[(((size_t)bb * 2 + c) * MODES + m) * HID + h];
                if (c) vsi[bb * HID + h] = vv; else vsr[bb * HID + h] = vv;
            }
            __syncthreads();
            int ol = t & 63, bq = t >> 6;
            int o = oh * 64 + ol;
            int b0 = bq * 2;
            const float2* a2 = At2 + ((size_t)m * HID) * HID + o;
            float are0 = 0, aim0 = 0, are1 = 0, aim1 = 0;
            #pragma unroll 4
            for (int h = 0; h < HID; ++h) {
                float2 a = a2[(size_t)h * HID];       // coalesced 512B
                float r0 = vsr[b0 * HID + h], i0 = vsi[b0 * HID + h];
                float r1 = vsr[(b0 + 1) * HID + h], i1 = vsi[(b0 + 1) * HID + h];
                are0 += a.x * r0 - a.y * i0;
                aim0 += a.y * r0 - a.x * i0;
                are1 += a.x * r1 - a.y * i1;
                aim1 += a.y * r1 - a.x * i1;
            }
            #pragma unroll
            for (int jb = 0; jb < 2; ++jb) {
                int bb = b0 + jb;
                float are = jb ? are1 : are0;
                float aim = jb ? aim1 : aim0;
                float fre = hf[(((size_t)bb * 2 + 0) * HID + o) * MODES + m];
                float fim = hf[(((size_t)bb * 2 + 1) * HID + o) * MODES + m];
                float vre = vsr[bb * HID + o];
                float vie = vsi[bb * HID + o];
                vnxt[(((size_t)bb * 2 + 0) * MODES + m) * HID + o] = vre + are + fre;
                vnxt[(((size_t)bb * 2 + 1) * MODES + m) * HID + o] = vie + aim + fim;
            }
            __syncthreads();
        } else if ((step & 15) == 15) {
            int w2 = w - 192;
            int fb = w2 >> 2, x0 = (w2 & 3) * 32;
            float* ftile = scratch;        // [16][128]
            int t0 = step - 15;
            for (int xi2 = 0; xi2 < 32; ++xi2) {
                int x = x0 + xi2;
                #pragma unroll
                for (int k = 0; k < 4; ++k) {
                    int tt = (t >> 7) + k * 4;
                    ftile[tt * HID + (t & 127)] =
                        zbuf[(((size_t)tt * BATCH + fb) * NX + x) * HID + (t & 127)];
                }
                __syncthreads();
                int h = t >> 2, tq = t & 3;
                float4 v4;
                v4.x = ftile[(tq * 4 + 0) * HID + h];
                v4.y = ftile[(tq * 4 + 1) * HID + h];
                v4.z = ftile[(tq * 4 + 2) * HID + h];
                v4.w = ftile[(tq * 4 + 3) * HID + h];
                *(float4*)&out[(((size_t)fb * HID + h) * NX + x) * NT + t0 + tq * 4] = v4;
                __syncthreads();
            }
        }
        bar();

        float* tmp = vcur; vcur = vnxt; vnxt = tmp;
    }

    // ---- final flush: all 256 WGs, columns 48..63 ----
    {
        float* ftile = scratch;
        int x0 = sub * 8;
        for (int xi2 = 0; xi2 < 8; ++xi2) {
            int x = x0 + xi2;
            #pragma unroll
            for (int k = 0; k < 4; ++k) {
                int tt = (t >> 7) + k * 4;
                ftile[tt * HID + (t & 127)] =
                    zbuf[(((size_t)tt * BATCH + b) * NX + x) * HID + (t & 127)];
            }
            __syncthreads();
            int h = t >> 2, tq = t & 3;
            float4 v4;
            v4.x = ftile[(tq * 4 + 0) * HID + h];
            v4.y = ftile[(tq * 4 + 1) * HID + h];
            v4.z = ftile[(tq * 4 + 2) * HID + h];
            v4.w = ftile[(tq * 4 + 3) * HID + h];
            *(float4*)&out[(((size_t)b * HID + h) * NX + x) * NT + 48 + tq * 4] = v4;
            __syncthreads();
        }
    }
}

// ---------------------------------------------------------------------------
extern "C" void kernel_launch(void* const* d_in, const int* in_sizes, int n_in,
                              void* d_out, int out_size, void* d_ws, size_t ws_size,
                              hipStream_t stream) {
    const float* z0 = (const float*)d_in[0];
    const float* xi = (const float*)d_in[1];
    const float* A  = (const float*)d_in[2];
    const float* WF = (const float*)d_in[3];
    const float* WG = (const float*)d_in[4];
    float* out = (float*)d_out;

    float* ws = (float*)d_ws;
    size_t off = 0;
    auto alloc = [&](size_t n) { float* p = ws + off; off += n; return p; };

    float*  Ct   = alloc((size_t)MODES * NX);
    float*  St   = alloc((size_t)MODES * NX);
    float2* T2x  = (float2*)alloc((size_t)NX * MODES * 2);
    float*  Wt   = alloc((size_t)HID * OM);
    float2* At2  = (float2*)alloc((size_t)MODES * HID * HID * 2);
    float*  va   = alloc((size_t)BATCH * 2 * MODES * HID);
    float*  vb   = alloc((size_t)BATCH * 2 * MODES * HID);
    float*  Hcb  = alloc((size_t)BATCH * NX * HID);
    float*  hfb  = alloc((size_t)BATCH * 2 * HID * MODES);
    float*  dxib = alloc((size_t)(NT - 1) * BATCH * NX * NF);
    float*  zbuf = alloc(16 * ZSZ);
    int*    barc = (int*)alloc(64);

    hipMemsetAsync(barc, 0, 64 * sizeof(int), stream);
    k_tables<<<MODES, 128, 0, stream>>>(Ct, St, T2x);
    {
        int total = (NT - 1) * BATCH * NX * NF;
        k_dxi<<<(total + 255) / 256, 256, 0, stream>>>(xi, dxib);
    }
    k_wt<<<dim3(4, 4, 5), dim3(32, 8), 0, stream>>>(WF, WG, Wt);
    k_at2<<<dim3(4, 4, MODES), dim3(32, 8), 0, stream>>>(A, At2);

    k_persist<<<NWG, TPB, 0, stream>>>(z0, Ct, St, T2x, Wt, At2, dxib,
                                       va, vb, Hcb, hfb, zbuf, out, barc);
}

// Round 6
// 6920.709 us; speedup vs baseline: 2.8253x; 2.8253x over previous
//
#include <hip/hip_runtime.h>
#include <math.h>

#define BATCH 16
#define HID   128
#define NX    128
#define NF    4
#define NT    64
#define MODES 96
#define OM    (5 * HID)     // 640 fused W rows (F + 4*G)
#define NWG   256
#define TPB   512
#define ZSZ   ((size_t)BATCH * NX * HID)

// ---------------------------------------------------------------------------
// Tables: C[m][x]=cos(2pi k_m x/128), S=sin, k_m=(80+m)%128; T2m[m][x]={c,s}
// ---------------------------------------------------------------------------
__global__ void k_tables(float* __restrict__ C, float* __restrict__ S,
                         float2* __restrict__ T2m) {
    int m = blockIdx.x, x = threadIdx.x;
    if (x < NX) {
        int k = (80 + m) % NX;
        float ang = (float)((k * x) & (NX - 1)) * (2.0f * (float)M_PI / (float)NX);
        float c = cosf(ang), s = sinf(ang);
        C[m * NX + x] = c;
        S[m * NX + x] = s;
        T2m[m * NX + x] = make_float2(c, s);
    }
}

// ---------------------------------------------------------------------------
// dxi[t][b][x][n] = xi[b,n,x,t+1] - xi[b,n,x,t]
// ---------------------------------------------------------------------------
__global__ void k_dxi(const float* __restrict__ xi, float* __restrict__ dxi) {
    int idx = blockIdx.x * blockDim.x + threadIdx.x;
    const int total = (NT - 1) * BATCH * NX * NF;
    if (idx < total) {
        int n = idx & (NF - 1);
        int x = (idx >> 2) & (NX - 1);
        int b = (idx >> 9) & (BATCH - 1);
        int t = idx >> 13;
        const float* base = xi + (((size_t)b * NF + n) * NX + x) * NT;
        dxi[idx] = base[t + 1] - base[t];
    }
}

// ---------------------------------------------------------------------------
// Wt[h][om], om = g*128+o: g=0 -> WF[o][h]; g=1..4 -> WG[o][g-1][h]
// ---------------------------------------------------------------------------
__global__ void k_wt(const float* __restrict__ WF, const float* __restrict__ WG,
                     float* __restrict__ Wt) {
    __shared__ float t[32][33];
    int g = blockIdx.z;
    int h0 = blockIdx.x * 32, o0 = blockIdx.y * 32;
    int tx = threadIdx.x, ty = threadIdx.y;
    #pragma unroll
    for (int j = 0; j < 32; j += 8) {
        int o = o0 + ty + j;
        t[ty + j][tx] = (g == 0) ? WF[(size_t)o * HID + h0 + tx]
                                 : WG[((size_t)o * NF + (g - 1)) * HID + h0 + tx];
    }
    __syncthreads();
    #pragma unroll
    for (int j = 0; j < 32; j += 8)
        Wt[(size_t)(h0 + ty + j) * OM + g * HID + o0 + tx] = t[tx][ty + j];
}

// ---------------------------------------------------------------------------
// At2[m][h][o] = {A[0][m][o][h], A[1][m][o][h]}
// ---------------------------------------------------------------------------
__global__ void k_at2(const float* __restrict__ A, float2* __restrict__ At2) {
    __shared__ float t0[32][33], t1[32][33];
    int m = blockIdx.z;
    int h0 = blockIdx.x * 32, o0 = blockIdx.y * 32;
    int tx = threadIdx.x, ty = threadIdx.y;
    const float* A0 = A + (size_t)m * HID * HID;
    const float* A1 = A0 + (size_t)MODES * HID * HID;
    #pragma unroll
    for (int j = 0; j < 32; j += 8) {
        t0[ty + j][tx] = A0[(size_t)(o0 + ty + j) * HID + h0 + tx];
        t1[ty + j][tx] = A1[(size_t)(o0 + ty + j) * HID + h0 + tx];
    }
    __syncthreads();
    #pragma unroll
    for (int j = 0; j < 32; j += 8)
        At2[((size_t)m * HID + h0 + ty + j) * HID + o0 + tx] =
            make_float2(t0[tx][ty + j], t1[tx][ty + j]);
}

// ---------------------------------------------------------------------------
// Persistent solver: 256 WGs x 512 thr. Grid barrier: release arrival,
// RELAXED polling (no per-iteration cache invalidate!), single acquire exit.
// ---------------------------------------------------------------------------
__global__ __launch_bounds__(TPB, 2) void k_persist(
    const float* __restrict__ z0, const float* __restrict__ Ct,
    const float* __restrict__ St, const float2* __restrict__ T2m,
    const float* __restrict__ Wt, const float2* __restrict__ At2,
    const float* __restrict__ dxi, float* __restrict__ va,
    float* __restrict__ vb, float* __restrict__ Hc,
    float* __restrict__ zbuf, float* __restrict__ out,
    int* __restrict__ barc)
{
    __shared__ float  Cs[MODES][8];
    __shared__ float  Ss[MODES][8];
    __shared__ float  zsh[HID][9];
    __shared__ float  dxs[8][NF];
    __shared__ float2 T2s[NX];
    __shared__ float  vsr[BATCH][HID];   // P3 v-slice; aliased as ftile by flush
    __shared__ float  vsi[BATCH][HID];

    const int w = blockIdx.x;
    const int t = threadIdx.x;
    const int b = w >> 4;
    const int sub = w & 15;
    const int xg0 = sub * 8;

    int nbar = 0;
    auto bar = [&]() {
        ++nbar;
        __syncthreads();
        if (t == 0) {
            __hip_atomic_fetch_add(barc, 1, __ATOMIC_RELEASE,
                                   __HIP_MEMORY_SCOPE_AGENT);
            while (__hip_atomic_load(barc, __ATOMIC_RELAXED,
                                     __HIP_MEMORY_SCOPE_AGENT) < NWG * nbar)
                __builtin_amdgcn_s_sleep(4);
            (void)__hip_atomic_load(barc, __ATOMIC_ACQUIRE,
                                    __HIP_MEMORY_SCOPE_AGENT);
        }
        __syncthreads();
    };

    // persistent P1 trig tables for this WG's x-tile
    for (int i = t; i < MODES * 8; i += TPB) {
        int m = i >> 3, xl = i & 7;
        Cs[m][xl] = Ct[m * NX + xg0 + xl];
        Ss[m][xl] = St[m * NX + xg0 + xl];
    }

    // ---- v0 phase: WG=(b, sub) computes v0[b][c][6 modes][h] ----
    {
        int h = t & 127, q = t >> 7;       // q 0..3
        int c = q & 1, mq = q >> 1;
        const float* zr = z0 + ((size_t)b * HID + h) * NX;
        const float* Tb = c ? St : Ct;
        #pragma unroll
        for (int j = 0; j < 3; ++j) {
            int m = sub * 6 + mq * 3 + j;
            const float* Trow = Tb + m * NX;
            float acc = 0.f;
            #pragma unroll 4
            for (int x = 0; x < NX; ++x) acc += zr[x] * Trow[x];
            if (c) acc = -acc;
            va[(((size_t)b * 2 + c) * MODES + m) * HID + h] = acc;
        }
    }
    bar();

    float* vcur = va;
    float* vnxt = vb;

    for (int step = 0; step < NT; ++step) {
        const int last = (step == NT - 1);

        // ---- P1: IDFT -> zsh (LDS) + zbuf slice ----
        {
            if (!last && t < 32)
                dxs[t >> 2][t & 3] =
                    dxi[(((size_t)step * BATCH + b) * NX + xg0 + (t >> 2)) * NF + (t & 3)];
            int h = t & 127, xp = t >> 7;
            int x0 = xp * 2;
            const float* vr = vcur + ((size_t)b * 2) * MODES * HID + h;
            const float* vi = vr + (size_t)MODES * HID;
            float a0 = 0.f, a1 = 0.f;
            #pragma unroll 4
            for (int m = 0; m < MODES; ++m) {
                float r = vr[m * HID], im = vi[m * HID];
                a0 += r * Cs[m][x0]     - im * Ss[m][x0];
                a1 += r * Cs[m][x0 + 1] - im * Ss[m][x0 + 1];
            }
            a0 *= 0.0078125f; a1 *= 0.0078125f;
            zsh[h][x0] = a0; zsh[h][x0 + 1] = a1;
            float* zsl = zbuf + (size_t)(step & 15) * ZSZ + ((size_t)b * NX + xg0) * HID;
            zsl[(size_t)x0 * HID + h] = a0;
            zsl[(size_t)(x0 + 1) * HID + h] = a1;
        }
        __syncthreads();
        if (last) { bar(); break; }

        // ---- P2 (WG-local): W-GEMM + tanh + dxi combine -> Hc ----
        {
            int x = t >> 6, oml = t & 63;
            float acc[10] = {0,0,0,0,0,0,0,0,0,0};
            const float* wp = Wt + oml;
            #pragma unroll 2
            for (int h = 0; h < HID; ++h) {
                float zv = zsh[h][x];                 // wave-broadcast
                const float* wr = wp + (size_t)h * OM;
                #pragma unroll
                for (int j = 0; j < 10; ++j)
                    acc[j] += wr[j * 64] * zv;
            }
            float d0 = dxs[x][0], d1 = dxs[x][1], d2 = dxs[x][2], d3 = dxs[x][3];
            #pragma unroll
            for (int oh = 0; oh < 2; ++oh) {
                float hv = tanhf(acc[oh])
                         + tanhf(acc[2 + oh]) * d0
                         + tanhf(acc[4 + oh]) * d1
                         + tanhf(acc[6 + oh]) * d2
                         + tanhf(acc[8 + oh]) * d3;
                Hc[((size_t)b * NX + xg0 + x) * HID + oh * 64 + oml] = hv;
            }
        }
        bar();

        // ---- P3: merged DFT + Av + update (w<192); flush (w>=192) ----
        if (w < 192) {
            int m = w >> 1, oh = w & 1;
            // stage trig row + v-slice
            if (t < NX) T2s[t] = T2m[(size_t)m * NX + t];
            #pragma unroll
            for (int k = 0; k < 8; ++k) {
                int idx = t + k * TPB;
                int h = idx & 127, bc = idx >> 7;
                int bb = bc >> 1, c = bc & 1;
                float vv = vcur[(((size_t)bb * 2 + c) * MODES + m) * HID + h];
                if (c) vsi[bb][h] = vv; else vsr[bb][h] = vv;
            }
            __syncthreads();
            int ol = t & 63, bq = t >> 6;       // 8 bq x 64 ol
            int o = oh * 64 + ol;
            int b0 = bq * 2;
            // DFT over x (coalesced Hc reads, broadcast trig)
            const float* hp0 = Hc + ((size_t)b0 * NX) * HID + o;
            const float* hp1 = hp0 + (size_t)NX * HID;
            float fre0 = 0, fim0 = 0, fre1 = 0, fim1 = 0;
            #pragma unroll 4
            for (int x = 0; x < NX; ++x) {
                float2 tt2 = T2s[x];
                float h0v = hp0[(size_t)x * HID];
                float h1v = hp1[(size_t)x * HID];
                fre0 += h0v * tt2.x; fim0 -= h0v * tt2.y;
                fre1 += h1v * tt2.x; fim1 -= h1v * tt2.y;
            }
            // Av over h (coalesced At2, broadcast v)
            const float2* a2 = At2 + ((size_t)m * HID) * HID + o;
            float are0 = 0, aim0 = 0, are1 = 0, aim1 = 0;
            #pragma unroll 4
            for (int h = 0; h < HID; ++h) {
                float2 a = a2[(size_t)h * HID];
                float r0 = vsr[b0][h],     i0 = vsi[b0][h];
                float r1 = vsr[b0 + 1][h], i1 = vsi[b0 + 1][h];
                are0 += a.x * r0 - a.y * i0;
                aim0 += a.y * r0 - a.x * i0;
                are1 += a.x * r1 - a.y * i1;
                aim1 += a.y * r1 - a.x * i1;
            }
            vnxt[(((size_t)b0 * 2 + 0) * MODES + m) * HID + o] = vsr[b0][o] + are0 + fre0;
            vnxt[(((size_t)b0 * 2 + 1) * MODES + m) * HID + o] = vsi[b0][o] + aim0 + fim0;
            vnxt[(((size_t)(b0 + 1) * 2 + 0) * MODES + m) * HID + o] = vsr[b0 + 1][o] + are1 + fre1;
            vnxt[(((size_t)(b0 + 1) * 2 + 1) * MODES + m) * HID + o] = vsi[b0 + 1][o] + aim1 + fim1;
            __syncthreads();
        } else if ((step & 15) == 15) {
            int w2 = w - 192;
            int fb = w2 >> 2, x0 = (w2 & 3) * 32;
            float* ftile = &vsr[0][0];     // 16*128 floats
            int t0 = step - 15;
            for (int xi2 = 0; xi2 < 32; ++xi2) {
                int x = x0 + xi2;
                #pragma unroll
                for (int k = 0; k < 4; ++k) {
                    int tt = (t >> 7) + k * 4;
                    ftile[tt * HID + (t & 127)] =
                        zbuf[(((size_t)tt * BATCH + fb) * NX + x) * HID + (t & 127)];
                }
                __syncthreads();
                int h = t >> 2, tq = t & 3;
                float4 v4;
                v4.x = ftile[(tq * 4 + 0) * HID + h];
                v4.y = ftile[(tq * 4 + 1) * HID + h];
                v4.z = ftile[(tq * 4 + 2) * HID + h];
                v4.w = ftile[(tq * 4 + 3) * HID + h];
                *(float4*)&out[(((size_t)fb * HID + h) * NX + x) * NT + t0 + tq * 4] = v4;
                __syncthreads();
            }
        }
        bar();

        float* tmp = vcur; vcur = vnxt; vnxt = tmp;
    }

    // ---- final flush: all 256 WGs, columns 48..63 ----
    {
        float* ftile = &vsr[0][0];
        int x0 = sub * 8;
        for (int xi2 = 0; xi2 < 8; ++xi2) {
            int x = x0 + xi2;
            #pragma unroll
            for (int k = 0; k < 4; ++k) {
                int tt = (t >> 7) + k * 4;
                ftile[tt * HID + (t & 127)] =
                    zbuf[(((size_t)tt * BATCH + b) * NX + x) * HID + (t & 127)];
            }
            __syncthreads();
            int h = t >> 2, tq = t & 3;
            float4 v4;
            v4.x = ftile[(tq * 4 + 0) * HID + h];
            v4.y = ftile[(tq * 4 + 1) * HID + h];
            v4.z = ftile[(tq * 4 + 2) * HID + h];
            v4.w = ftile[(tq * 4 + 3) * HID + h];
            *(float4*)&out[(((size_t)b * HID + h) * NX + x) * NT + 48 + tq * 4] = v4;
            __syncthreads();
        }
    }
}

// ---------------------------------------------------------------------------
extern "C" void kernel_launch(void* const* d_in, const int* in_sizes, int n_in,
                              void* d_out, int out_size, void* d_ws, size_t ws_size,
                              hipStream_t stream) {
    const float* z0 = (const float*)d_in[0];
    const float* xi = (const float*)d_in[1];
    const float* A  = (const float*)d_in[2];
    const float* WF = (const float*)d_in[3];
    const float* WG = (const float*)d_in[4];
    float* out = (float*)d_out;

    float* ws = (float*)d_ws;
    size_t off = 0;
    auto alloc = [&](size_t n) { float* p = ws + off; off += n; return p; };

    float*  Ct   = alloc((size_t)MODES * NX);
    float*  St   = alloc((size_t)MODES * NX);
    float2* T2m  = (float2*)alloc((size_t)MODES * NX * 2);
    float*  Wt   = alloc((size_t)HID * OM);
    float2* At2  = (float2*)alloc((size_t)MODES * HID * HID * 2);
    float*  va   = alloc((size_t)BATCH * 2 * MODES * HID);
    float*  vb   = alloc((size_t)BATCH * 2 * MODES * HID);
    float*  Hcb  = alloc((size_t)BATCH * NX * HID);
    float*  dxib = alloc((size_t)(NT - 1) * BATCH * NX * NF);
    float*  zbuf = alloc(16 * ZSZ);
    int*    barc = (int*)alloc(64);

    hipMemsetAsync(barc, 0, 64 * sizeof(int), stream);
    k_tables<<<MODES, 128, 0, stream>>>(Ct, St, T2m);
    {
        int total = (NT - 1) * BATCH * NX * NF;
        k_dxi<<<(total + 255) / 256, 256, 0, stream>>>(xi, dxib);
    }
    k_wt<<<dim3(4, 4, 5), dim3(32, 8), 0, stream>>>(WF, WG, Wt);
    k_at2<<<dim3(4, 4, MODES), dim3(32, 8), 0, stream>>>(A, At2);

    k_persist<<<NWG, TPB, 0, stream>>>(z0, Ct, St, T2m, Wt, At2, dxib,
                                       va, vb, Hcb, zbuf, out, barc);
}